// Round 2
// baseline (15.208 us; speedup 1.0000x reference)
//
#include <hip/hip_runtime.h>

#define NG     4096
#define NPOSE  2
#define HW     16384
#define FXc    120.0f
#define FYc    120.0f
#define CXc    64.0f
#define CYc    64.0f
#define LOG2E  1.4426950408889634f

#if __has_builtin(__builtin_amdgcn_exp2f)
#define EXP2F(x) __builtin_amdgcn_exp2f(x)
#else
#define EXP2F(x) exp2f(x)
#endif

// ---------------------------------------------------------------------------
// Kernel 1: per (pose, gaussian) precompute.
// ws layout: float4 G[NPOSE*NG]  = {pjx, pjy, s2, log2(opacity)}
//            float4 C[NPOSE*NG]  = {r, g, b, 0}   (after G)
// ---------------------------------------------------------------------------
__global__ void prep_kernel(const float* __restrict__ pos,
                            const float* __restrict__ col,
                            const float* __restrict__ opa,
                            const float* __restrict__ scl,
                            const float* __restrict__ qv,
                            const float* __restrict__ tv,
                            float4* __restrict__ ws) {
    int i = blockIdx.x * 256 + threadIdx.x;
    if (i >= NPOSE * NG) return;
    int pose = i >> 12;
    int n    = i & (NG - 1);

    float q0 = qv[pose * 4 + 0], q1 = qv[pose * 4 + 1];
    float q2 = qv[pose * 4 + 2], q3 = qv[pose * 4 + 3];
    float nrm = sqrtf(q0 * q0 + q1 * q1 + q2 * q2 + q3 * q3);
    float w = q0 / nrm, x = q1 / nrm, y = q2 / nrm, z = q3 / nrm;

    float r00 = 1.0f - 2.0f * (y * y + z * z);
    float r01 = 2.0f * (x * y - z * w);
    float r02 = 2.0f * (x * z + y * w);
    float r10 = 2.0f * (x * y + z * w);
    float r11 = 1.0f - 2.0f * (x * x + z * z);
    float r12 = 2.0f * (y * z - x * w);
    float r20 = 2.0f * (x * z - y * w);
    float r21 = 2.0f * (y * z + x * w);
    float r22 = 1.0f - 2.0f * (x * x + y * y);

    float t0 = tv[pose * 3 + 0], t1 = tv[pose * 3 + 1], t2 = tv[pose * 3 + 2];
    float px = pos[n * 3 + 0], py = pos[n * 3 + 1], pz = pos[n * 3 + 2];

    float cx = r00 * px + r01 * py + r02 * pz + t0;
    float cy = r10 * px + r11 * py + r12 * pz + t1;
    float cz = r20 * px + r21 * py + r22 * pz + t2;

    float pjx = cx / cz * FXc + CXc;
    float pjy = cy / cz * FYc + CYc;

    float sc  = scl[n];
    float var = sc * sc;
    float s2  = (-0.5f * LOG2E) / var;       // exp(-0.5*d2/var) == 2^(s2*d2)
    float lop = log2f(opa[n]);               // fold opacity into the exponent

    ws[i]               = make_float4(pjx, pjy, s2, lop);
    ws[NPOSE * NG + i]  = make_float4(col[n * 3 + 0], col[n * 3 + 1],
                                      col[n * 3 + 2], 0.0f);
}

// ---------------------------------------------------------------------------
// Kernel 2: render. One block = 64 consecutive pixels (a row segment) x 8
// gaussian slices. Phase 1: cull all 4096 gaussians against the block's pixel
// box (conservative bound), compact survivor indices into LDS. Phase 2:
// survivor loop with per-slice partial accumulators. Phase 3: LDS reduce +
// final divide + tiled store.
// Cull bound safety: dropped gaussians have w < 2^-110 each; total dropped
// contribution <= 4096 * 2^-110 / 1e-8 ~ 3e-22 << threshold 7.9e-18.
// ---------------------------------------------------------------------------
__global__ __launch_bounds__(512, 4) void render_kernel(
        const float4* __restrict__ ws, float* __restrict__ out) {
    __shared__ unsigned short list[NG];
    __shared__ int lcount;
    __shared__ float4 red[8][64];

    const int tid    = threadIdx.x;
    const int lane   = tid & 63;
    const int wave   = tid >> 6;
    const int blk    = blockIdx.x;       // 0..511
    const int pose   = blk >> 8;         // 256 pixel-blocks per pose
    const int pixblk = blk & 255;
    const int pid    = pixblk * 64 + lane;     // 0..16383
    const float fx   = (float)(pid & 127);
    const float fy   = (float)(pid >> 7);

    // block pixel bounding box: single row Y, x in [X0, X0+63]
    const float Yf = (float)(pixblk >> 1);
    const float X0 = (float)((pixblk & 1) * 64);
    const float X1 = X0 + 63.0f;

    if (tid == 0) lcount = 0;
    __syncthreads();

    const float4* __restrict__ Gt = ws + (size_t)pose * NG;
    const float4* __restrict__ Ct = ws + (size_t)NPOSE * NG + (size_t)pose * NG;

    // ---- Phase 1: cull + ballot compaction (8 rounds x 512 threads) ----
    for (int r = 0; r < 8; ++r) {
        int g = r * 512 + tid;
        float4 a = Gt[g];
        float dxm = fmaxf(fmaxf(X0 - a.x, a.x - X1), 0.0f);
        float dym = fabsf(a.y - Yf);
        float argmax = fmaf(fmaf(dxm, dxm, dym * dym), a.z, a.w); // best case
        bool keep = argmax >= -110.0f;
        unsigned long long mask = __ballot(keep);
        int cnt = __popcll(mask);
        int base = 0;
        if (lane == 0 && cnt) base = atomicAdd(&lcount, cnt);
        base = __shfl(base, 0);
        if (keep) {
            int posn = __popcll(mask & ((1ull << lane) - 1ull));
            list[base + posn] = (unsigned short)g;
        }
    }
    __syncthreads();
    const int L = lcount;

    // ---- Phase 2: survivor loop (wave w takes i = w, w+8, w+16, ...) ----
    float accR = 0.0f, accG = 0.0f, accB = 0.0f, accD = 0.0f;
    for (int i = wave; i < L; i += 8) {
        int g = __builtin_amdgcn_readfirstlane((int)list[i]); // wave-uniform
        float4 a = Gt[g];
        float4 c = Ct[g];
        float dx = fx - a.x;
        float dy = fy - a.y;
        float d2 = fmaf(dx, dx, dy * dy);
        float arg = fmaf(d2, a.z, a.w);
        float e = EXP2F(arg);            // = opacity * exp(-0.5*d2/var)
        accD += e;
        accR = fmaf(e, c.x, accR);
        accG = fmaf(e, c.y, accG);
        accB = fmaf(e, c.z, accB);
    }

    // ---- Phase 3: cross-slice reduction + store ----
    red[wave][lane] = make_float4(accR, accG, accB, accD);
    __syncthreads();
    if (tid < 64) {
        float4 s = red[0][lane];
#pragma unroll
        for (int w2 = 1; w2 < 8; ++w2) {
            float4 t = red[w2][lane];
            s.x += t.x; s.y += t.y; s.z += t.z; s.w += t.w;
        }
        float den = s.w + 1e-8f;
        int t  = pid >> 10;          // tile index (8 rows per tile)
        int pl = pid & 1023;         // position within tile (32x32 row-major)
        float* o = out + ((size_t)(pose * 16 + t) * 3) * 1024 + pl;
        o[0]    = s.x / den;
        o[1024] = s.y / den;
        o[2048] = s.z / den;
    }
}

extern "C" void kernel_launch(void* const* d_in, const int* in_sizes, int n_in,
                              void* d_out, int out_size, void* d_ws, size_t ws_size,
                              hipStream_t stream) {
    const float* pos = (const float*)d_in[0];
    const float* col = (const float*)d_in[1];
    const float* opa = (const float*)d_in[2];
    const float* scl = (const float*)d_in[3];
    const float* qv  = (const float*)d_in[4];
    const float* tv  = (const float*)d_in[5];
    float* out = (float*)d_out;
    float4* ws = (float4*)d_ws;   // needs 2*NPOSE*NG*16 = 256 KiB

    prep_kernel<<<(NPOSE * NG + 255) / 256, 256, 0, stream>>>(
        pos, col, opa, scl, qv, tv, ws);
    render_kernel<<<NPOSE * HW / 64, 512, 0, stream>>>(ws, out);
}

// Round 3
// 10.278 us; speedup vs baseline: 1.4796x; 1.4796x over previous
//
#include <hip/hip_runtime.h>

#define NG     4096
#define NPOSE  2
#define FXc    120.0f
#define FYc    120.0f
#define CXc    64.0f
#define CYc    64.0f
#define HLOG2E 0.7213475204444817f   // 0.5 * log2(e)

#if __has_builtin(__builtin_amdgcn_exp2f)
#define EXP2F(x) __builtin_amdgcn_exp2f(x)
#else
#define EXP2F(x) exp2f(x)
#endif
#if __has_builtin(__builtin_amdgcn_logf)
#define LOG2F(x) __builtin_amdgcn_logf(x)
#else
#define LOG2F(x) log2f(x)
#endif
#if __has_builtin(__builtin_amdgcn_rcpf)
#define RCPF(x) __builtin_amdgcn_rcpf(x)
#else
#define RCPF(x) (1.0f / (x))
#endif

// ---------------------------------------------------------------------------
// Single fused kernel. One block = one image row of one pose (128 pixels),
// 512 threads = 8 waves: waves split as (pixgroup = wave&1) x (slice = wave>>1).
//
// Phase 1 (cull): each thread projects 8 gaussians inline (R recomputed per
// thread, wave-uniform) and tests the row bounding box:
//   keep  iff  HLOG2E * d2min <= 110 * var
// (equivalent to best-case exponent >= -110 given opacity <= 1).
// Dropped contribution <= 4096 * 2^-110 / 1e-8 ~ 3e-22 << pass threshold.
// Survivor indices are ballot-compacted into an 8 KB LDS list (no overflow
// possible: list holds all 4096).
//
// Phase 2 (render): slices stride the survivor list; per survivor the wave
// recomputes projection from globals (wave-uniform addresses -> scalar loads)
// and accumulates w = 2^(s2*d2 + log2(op)) and w*color per pixel.
//
// Phase 3: LDS reduce across the 4 slices, divide, tiled store.
// ---------------------------------------------------------------------------
__global__ __launch_bounds__(512, 4) void render_fused(
        const float* __restrict__ pos,
        const float* __restrict__ col,
        const float* __restrict__ opa,
        const float* __restrict__ scl,
        const float* __restrict__ qv,
        const float* __restrict__ tv,
        float* __restrict__ out) {
    __shared__ unsigned short list[NG];
    __shared__ int lcount;
    __shared__ float4 red[8][64];

    const int tid   = threadIdx.x;
    const int lane  = tid & 63;
    const int wave  = tid >> 6;
    const int blk   = blockIdx.x;          // 0..255
    const int pose  = blk >> 7;            // 128 rows per pose
    const int row   = blk & 127;
    const int pg    = wave & 1;            // pixel group (0: x 0..63, 1: x 64..127)
    const int slice = wave >> 1;           // gaussian slice 0..3
    const float fx  = (float)(pg * 64 + lane);
    const float fy  = (float)row;

    // ---- rotation matrix + translation (wave-uniform; scalarized loads) ----
    float q0 = qv[pose * 4 + 0], q1 = qv[pose * 4 + 1];
    float q2 = qv[pose * 4 + 2], q3 = qv[pose * 4 + 3];
    float inrm = RCPF(sqrtf(q0 * q0 + q1 * q1 + q2 * q2 + q3 * q3));
    float w = q0 * inrm, x = q1 * inrm, y = q2 * inrm, z = q3 * inrm;
    float r00 = 1.0f - 2.0f * (y * y + z * z);
    float r01 = 2.0f * (x * y - z * w);
    float r02 = 2.0f * (x * z + y * w);
    float r10 = 2.0f * (x * y + z * w);
    float r11 = 1.0f - 2.0f * (x * x + z * z);
    float r12 = 2.0f * (y * z - x * w);
    float r20 = 2.0f * (x * z - y * w);
    float r21 = 2.0f * (y * z + x * w);
    float r22 = 1.0f - 2.0f * (x * x + y * y);
    float t0 = tv[pose * 3 + 0], t1 = tv[pose * 3 + 1], t2 = tv[pose * 3 + 2];

    if (tid == 0) lcount = 0;
    __syncthreads();

    // ---- Phase 1: inline-projection cull + ballot compaction ----
    for (int r = 0; r < NG / 512; ++r) {
        int g = r * 512 + tid;
        float px = pos[g * 3 + 0], py = pos[g * 3 + 1], pz = pos[g * 3 + 2];
        float cz = fmaf(r20, px, fmaf(r21, py, fmaf(r22, pz, t2)));
        float cx = fmaf(r00, px, fmaf(r01, py, fmaf(r02, pz, t0)));
        float cy = fmaf(r10, px, fmaf(r11, py, fmaf(r12, pz, t1)));
        float iz = RCPF(cz);
        float pjx = fmaf(cx * iz, FXc, CXc);
        float pjy = fmaf(cy * iz, FYc, CYc);
        float sc  = scl[g];
        float var = sc * sc;
        // row box: y == fyrow exactly, x in [0,127]
        float dxm = fmaxf(fmaxf(-pjx, pjx - 127.0f), 0.0f);
        float dy  = pjy - fy;   // note: fy == row for every wave in this block
        float d2m = fmaf(dxm, dxm, dy * dy);
        bool keep = fmaf(d2m, HLOG2E, -110.0f * var) <= 0.0f;
        unsigned long long mask = __ballot(keep);
        int cnt = __popcll(mask);
        int base = 0;
        if (lane == 0 && cnt) base = atomicAdd(&lcount, cnt);
        base = __shfl(base, 0);
        if (keep) {
            int posn = __popcll(mask & ((1ull << lane) - 1ull));
            list[base + posn] = (unsigned short)g;
        }
    }
    __syncthreads();
    const int L = lcount;

    // ---- Phase 2: survivor loop (slice s takes i = s, s+4, ...) ----
    float accR = 0.0f, accG = 0.0f, accB = 0.0f, accD = 0.0f;
    for (int i = slice; i < L; i += 4) {
        int g = __builtin_amdgcn_readfirstlane((int)list[i]); // wave-uniform
        float px = pos[g * 3 + 0], py = pos[g * 3 + 1], pz = pos[g * 3 + 2];
        float cz = fmaf(r20, px, fmaf(r21, py, fmaf(r22, pz, t2)));
        float cx = fmaf(r00, px, fmaf(r01, py, fmaf(r02, pz, t0)));
        float cy = fmaf(r10, px, fmaf(r11, py, fmaf(r12, pz, t1)));
        float iz = RCPF(cz);
        float pjx = fmaf(cx * iz, FXc, CXc);
        float pjy = fmaf(cy * iz, FYc, CYc);
        float sc  = scl[g];
        float s2  = -HLOG2E * RCPF(sc * sc);
        float lop = LOG2F(opa[g]);
        float cr = col[g * 3 + 0], cg = col[g * 3 + 1], cb = col[g * 3 + 2];
        float dx = fx - pjx;
        float dy = fy - pjy;
        float d2 = fmaf(dx, dx, dy * dy);
        float e  = EXP2F(fmaf(d2, s2, lop));  // opacity * exp(-0.5*d2/var)
        accD += e;
        accR = fmaf(e, cr, accR);
        accG = fmaf(e, cg, accG);
        accB = fmaf(e, cb, accB);
    }

    // ---- Phase 3: reduce across slices + store ----
    red[wave][lane] = make_float4(accR, accG, accB, accD);
    __syncthreads();
    if (tid < 128) {
        int pg2 = tid >> 6, ln = tid & 63;
        float4 s = red[pg2][ln];
#pragma unroll
        for (int sl = 1; sl < 4; ++sl) {
            float4 t = red[pg2 + 2 * sl][ln];
            s.x += t.x; s.y += t.y; s.z += t.z; s.w += t.w;
        }
        float den = s.w + 1e-8f;
        int pid = row * 128 + pg2 * 64 + ln;
        int tl  = pid >> 10;         // tile index
        int pl  = pid & 1023;        // position within tile
        float* o = out + ((size_t)(pose * 16 + tl) * 3) * 1024 + pl;
        o[0]    = s.x / den;
        o[1024] = s.y / den;
        o[2048] = s.z / den;
    }
}

extern "C" void kernel_launch(void* const* d_in, const int* in_sizes, int n_in,
                              void* d_out, int out_size, void* d_ws, size_t ws_size,
                              hipStream_t stream) {
    const float* pos = (const float*)d_in[0];
    const float* col = (const float*)d_in[1];
    const float* opa = (const float*)d_in[2];
    const float* scl = (const float*)d_in[3];
    const float* qv  = (const float*)d_in[4];
    const float* tv  = (const float*)d_in[5];
    float* out = (float*)d_out;

    render_fused<<<NPOSE * 128, 512, 0, stream>>>(pos, col, opa, scl, qv, tv, out);
}